// Round 1
// baseline (822.779 us; speedup 1.0000x reference)
//
#include <hip/hip_runtime.h>

#define N_NODES 10000
#define N_EDGES 100000
#define IN_CH 64
#define EDGE_DIM 16
#define HID 128
#define HEADS 4
#define HC 512          // HEADS*HID
#define LAYERS 4
#define NUM_GRAPHS 256

__device__ __forceinline__ float elu_f(float x) { return x > 0.f ? x : (__expf(x) - 1.f); }

// ---------------- h0 = elu(x @ Win + b_in), M=10000 K=64 N=128 ----------------
__global__ __launch_bounds__(128) void k_init_h(const float* __restrict__ x,
                                                const float* __restrict__ Win,
                                                const float* __restrict__ b_in,
                                                float* __restrict__ h) {
    __shared__ float xs[IN_CH];
    int n = blockIdx.x, t = threadIdx.x;
    if (t < IN_CH) xs[t] = x[(size_t)n * IN_CH + t];
    __syncthreads();
    float s = b_in[t];
#pragma unroll 8
    for (int k = 0; k < IN_CH; k++) s = fmaf(xs[k], Win[k * HID + t], s);
    h[(size_t)n * HID + t] = elu_f(s);
}

// ---------------- generic fp32 GEMM: C[M,N] = A[M,128] @ B[128,N] + bias ------
// grid (ceil(M/128), N/128), block 256. 64 outputs/thread.
__global__ __launch_bounds__(256) void k_gemm128(const float* __restrict__ A,
                                                 const float* __restrict__ B,
                                                 const float* __restrict__ bias,
                                                 float* __restrict__ C,
                                                 int M, int N) {
    __shared__ float As[16][128];
    __shared__ float Bs[16][128];
    int t = threadIdx.x;
    int tx = t & 15, ty = t >> 4;
    int row0 = blockIdx.x * 128;
    int c0 = blockIdx.y * 128;
    float acc[8][8];
#pragma unroll
    for (int i = 0; i < 8; i++)
#pragma unroll
        for (int j = 0; j < 8; j++) acc[i][j] = 0.f;

    for (int kb = 0; kb < 128; kb += 16) {
#pragma unroll
        for (int i = 0; i < 8; i++) {
            int idx = t + i * 256;
            int m = idx >> 4, k = idx & 15;
            int r = row0 + m; if (r >= M) r = M - 1;
            As[k][m] = A[(size_t)r * 128 + kb + k];
        }
#pragma unroll
        for (int i = 0; i < 8; i++) {
            int idx = t + i * 256;
            int k = idx >> 7, c = idx & 127;
            Bs[k][c] = B[(size_t)(kb + k) * N + c0 + c];
        }
        __syncthreads();
#pragma unroll
        for (int k = 0; k < 16; k++) {
            float a[8], b[8];
            float4 a0 = *(const float4*)&As[k][ty * 8];
            float4 a1 = *(const float4*)&As[k][ty * 8 + 4];
            a[0] = a0.x; a[1] = a0.y; a[2] = a0.z; a[3] = a0.w;
            a[4] = a1.x; a[5] = a1.y; a[6] = a1.z; a[7] = a1.w;
#pragma unroll
            for (int j = 0; j < 8; j++) b[j] = Bs[k][tx + 16 * j];
#pragma unroll
            for (int i = 0; i < 8; i++)
#pragma unroll
                for (int j = 0; j < 8; j++) acc[i][j] = fmaf(a[i], b[j], acc[i][j]);
        }
        __syncthreads();
    }
    float bj[8];
#pragma unroll
    for (int j = 0; j < 8; j++) bj[j] = bias[c0 + tx + 16 * j];
#pragma unroll
    for (int i = 0; i < 8; i++) {
        int r = row0 + ty * 8 + i;
        if (r < M) {
#pragma unroll
            for (int j = 0; j < 8; j++)
                C[(size_t)r * N + c0 + tx + 16 * j] = acc[i][j] + bj[j];
        }
    }
}

// ---------------- CSR build ----------------
__global__ void k_degree(const int* __restrict__ ei, int* __restrict__ deg) {
    int e = blockIdx.x * blockDim.x + threadIdx.x;
    if (e < N_EDGES) atomicAdd(&deg[ei[N_EDGES + e]], 1);
}

__global__ __launch_bounds__(1024) void k_scan(const int* __restrict__ deg,
                                               int* __restrict__ row_start,
                                               int* __restrict__ cursor) {
    __shared__ int buf[1024];
    __shared__ int carry_s;
    int t = threadIdx.x;
    if (t == 0) { carry_s = 0; row_start[0] = 0; }
    __syncthreads();
    for (int base = 0; base < N_NODES; base += 1024) {
        int i = base + t;
        int v = (i < N_NODES) ? deg[i] : 0;
        buf[t] = v;
        __syncthreads();
        for (int off = 1; off < 1024; off <<= 1) {
            int add = (t >= off) ? buf[t - off] : 0;
            __syncthreads();
            buf[t] += add;
            __syncthreads();
        }
        int incl = buf[t];
        int carry = carry_s;
        if (i < N_NODES) {
            row_start[i + 1] = carry + incl;
            cursor[i] = carry + incl - v;   // exclusive prefix
        }
        __syncthreads();
        if (t == 1023) carry_s = carry + buf[1023];
        __syncthreads();
    }
}

__global__ void k_scatter(const int* __restrict__ ei, int* __restrict__ cursor,
                          int* __restrict__ ssrc, int* __restrict__ seid) {
    int e = blockIdx.x * blockDim.x + threadIdx.x;
    if (e < N_EDGES) {
        int d = ei[N_EDGES + e];
        int pos = atomicAdd(&cursor[d], 1);
        ssrc[pos] = ei[e];
        seid[pos] = e;
    }
}

// ---------------- fused GATv2 edge phase + head-mean + LN + ELU + residual ----
// one block (128 thr = 2 waves) per destination node. wave w owns heads {2w,2w+1};
// lane owns 4 channels: c0 = w*256 + lane*4. We columns kept in 64 VGPRs.
__global__ __launch_bounds__(128) void k_edge_fused(
    const float* __restrict__ xl, const float* __restrict__ xr,
    const float* __restrict__ edge_attr,
    const int* __restrict__ row_start, const int* __restrict__ ssrc,
    const int* __restrict__ seid,
    const float* __restrict__ We_l, const float* __restrict__ att_l,
    const float* __restrict__ bgat_l, const float* __restrict__ gamma_l,
    const float* __restrict__ beta_l,
    const float* __restrict__ resbuf, int has_res,
    float* __restrict__ h_out) {
    int n = blockIdx.x;
    int t = threadIdx.x;
    int wave = t >> 6;
    int lane = t & 63;
    int c0 = wave * 256 + lane * 4;
    int head = c0 >> 7;

    float4 we4[16];
#pragma unroll
    for (int k = 0; k < 16; k++) we4[k] = *(const float4*)(We_l + k * HC + c0);
    float4 att4 = *(const float4*)(att_l + head * HID + (c0 & 127));
    float4 xr4  = *(const float4*)(xr + (size_t)n * HC + c0);

    float4 acc = {0.f, 0.f, 0.f, 0.f};
    float m_run = -1e30f, l_run = 0.f;

    int e0 = row_start[n], e1 = row_start[n + 1];
    for (int j = e0; j < e1; j++) {
        int s = ssrc[j], eid = seid[j];
        float ea[16];
        {
            const float4* eap = (const float4*)(edge_attr + (size_t)eid * EDGE_DIM);
            float4 a0 = eap[0], a1 = eap[1], a2 = eap[2], a3 = eap[3];
            ea[0]=a0.x; ea[1]=a0.y; ea[2]=a0.z; ea[3]=a0.w;
            ea[4]=a1.x; ea[5]=a1.y; ea[6]=a1.z; ea[7]=a1.w;
            ea[8]=a2.x; ea[9]=a2.y; ea[10]=a2.z; ea[11]=a2.w;
            ea[12]=a3.x; ea[13]=a3.y; ea[14]=a3.z; ea[15]=a3.w;
        }
        float4 xl4 = *(const float4*)(xl + (size_t)s * HC + c0);
        float4 e4 = {0.f, 0.f, 0.f, 0.f};
#pragma unroll
        for (int k = 0; k < 16; k++) {
            e4.x = fmaf(ea[k], we4[k].x, e4.x);
            e4.y = fmaf(ea[k], we4[k].y, e4.y);
            e4.z = fmaf(ea[k], we4[k].z, e4.z);
            e4.w = fmaf(ea[k], we4[k].w, e4.w);
        }
        float mx = xl4.x + xr4.x + e4.x; mx = mx > 0.f ? mx : 0.2f * mx;
        float my = xl4.y + xr4.y + e4.y; my = my > 0.f ? my : 0.2f * my;
        float mz = xl4.z + xr4.z + e4.z; mz = mz > 0.f ? mz : 0.2f * mz;
        float mw = xl4.w + xr4.w + e4.w; mw = mw > 0.f ? mw : 0.2f * mw;
        float partial = mx * att4.x + my * att4.y + mz * att4.z + mw * att4.w;
#pragma unroll
        for (int off = 1; off < 32; off <<= 1) partial += __shfl_xor(partial, off, 64);
        float logit = partial;                 // per-head logit, uniform in 32-lane half
        float nm = fmaxf(m_run, logit);
        float sc = __expf(m_run - nm);
        float p  = __expf(logit - nm);
        l_run = l_run * sc + p;
        acc.x = fmaf(p, xl4.x, acc.x * sc);
        acc.y = fmaf(p, xl4.y, acc.y * sc);
        acc.z = fmaf(p, xl4.z, acc.z * sc);
        acc.w = fmaf(p, xl4.w, acc.w * sc);
        m_run = nm;
    }
    float inv = 1.f / (l_run + 1e-16f);

    __shared__ float sout[HC];
    __shared__ float red[4];
    sout[c0 + 0] = acc.x * inv;
    sout[c0 + 1] = acc.y * inv;
    sout[c0 + 2] = acc.z * inv;
    sout[c0 + 3] = acc.w * inv;
    __syncthreads();

    int c = t;
    float v = 0.25f * (sout[c] + sout[c + 128] + sout[c + 256] + sout[c + 384]) + bgat_l[c];
    float s1 = v, s2 = v * v;
#pragma unroll
    for (int off = 1; off < 64; off <<= 1) {
        s1 += __shfl_xor(s1, off, 64);
        s2 += __shfl_xor(s2, off, 64);
    }
    if (lane == 0) { red[wave * 2] = s1; red[wave * 2 + 1] = s2; }
    __syncthreads();
    s1 = red[0] + red[2];
    s2 = red[1] + red[3];
    float mu = s1 * (1.f / HID);
    float var = s2 * (1.f / HID) - mu * mu;
    float rstd = rsqrtf(var + 1e-5f);
    float y = fmaf(gamma_l[c] * (v - mu), rstd, beta_l[c]);
    y = elu_f(y);
    if (has_res) y += resbuf[(size_t)n * HID + c];
    h_out[(size_t)n * HID + c] = y;
}

// ---------------- pooling + MLP ----------------
__global__ __launch_bounds__(128) void k_pool(const float* __restrict__ h,
                                              const int* __restrict__ batch,
                                              float* __restrict__ hsum,
                                              int* __restrict__ cnt) {
    int n = blockIdx.x, c = threadIdx.x;
    int g = batch[n];
    atomicAdd(&hsum[(size_t)g * HID + c], h[(size_t)n * HID + c]);
    if (c == 0) atomicAdd(&cnt[g], 1);
}

__global__ __launch_bounds__(128) void k_mlp(const float* __restrict__ hsum,
                                             const int* __restrict__ cnt,
                                             const float* __restrict__ W1, const float* __restrict__ b1,
                                             const float* __restrict__ W2, const float* __restrict__ b2,
                                             const float* __restrict__ W3, const float* __restrict__ b3,
                                             float* __restrict__ out) {
    int g = blockIdx.x, t = threadIdx.x;
    __shared__ float hg[HID], z1[HID], z2[64];
    float invc = 1.f / fmaxf((float)cnt[g], 1.f);
    hg[t] = hsum[(size_t)g * HID + t] * invc;
    __syncthreads();
    float s = b1[t];
#pragma unroll 8
    for (int k = 0; k < HID; k++) s = fmaf(hg[k], W1[k * HID + t], s);
    z1[t] = fmaxf(s, 0.f);
    __syncthreads();
    if (t < 64) {
        float s2 = b2[t];
#pragma unroll 8
        for (int k = 0; k < HID; k++) s2 = fmaf(z1[k], W2[k * 64 + t], s2);
        z2[t] = fmaxf(s2, 0.f);
    }
    __syncthreads();
    if (t < 64) {
        float s3 = z2[t] * W3[t];
#pragma unroll
        for (int off = 1; off < 64; off <<= 1) s3 += __shfl_xor(s3, off, 64);
        if (t == 0) out[g] = s3 + b3[0];
    }
}

// ---------------- host launcher ----------------
extern "C" void kernel_launch(void* const* d_in, const int* in_sizes, int n_in,
                              void* d_out, int out_size, void* d_ws, size_t ws_size,
                              hipStream_t stream) {
    const float* x         = (const float*)d_in[0];
    const int*   ei        = (const int*)  d_in[1];
    const float* edge_attr = (const float*)d_in[2];
    const int*   batch     = (const int*)  d_in[3];
    const float* Win       = (const float*)d_in[4];
    const float* b_in      = (const float*)d_in[5];
    const float* Wl        = (const float*)d_in[6];
    const float* bl        = (const float*)d_in[7];
    const float* Wr        = (const float*)d_in[8];
    const float* br        = (const float*)d_in[9];
    const float* We        = (const float*)d_in[10];
    const float* att       = (const float*)d_in[11];
    const float* b_gat     = (const float*)d_in[12];
    const float* gamma     = (const float*)d_in[13];
    const float* beta      = (const float*)d_in[14];
    const float* Wres      = (const float*)d_in[15];
    const float* bres      = (const float*)d_in[16];
    const float* W1        = (const float*)d_in[17];
    const float* b1        = (const float*)d_in[18];
    const float* W2        = (const float*)d_in[19];
    const float* b2        = (const float*)d_in[20];
    const float* W3        = (const float*)d_in[21];
    const float* b3        = (const float*)d_in[22];
    float* out = (float*)d_out;

    char* ws = (char*)d_ws;
    size_t off = 0;
    auto alloc = [&](size_t bytes) -> void* {
        void* p = ws + off;
        off = (off + bytes + 255) & ~(size_t)255;
        return p;
    };
    float* h0      = (float*)alloc((size_t)N_NODES * HID * 4);
    float* h1      = (float*)alloc((size_t)N_NODES * HID * 4);
    float* resbuf  = (float*)alloc((size_t)N_NODES * HID * 4);
    float* xl      = (float*)alloc((size_t)N_NODES * HC * 4);
    float* xr      = (float*)alloc((size_t)N_NODES * HC * 4);
    float* hsum    = (float*)alloc((size_t)NUM_GRAPHS * HID * 4);
    int*   cnt     = (int*)  alloc((size_t)NUM_GRAPHS * 4);
    int*   deg     = (int*)  alloc((size_t)N_NODES * 4);
    int*   rowst   = (int*)  alloc((size_t)(N_NODES + 1) * 4);
    int*   cursor  = (int*)  alloc((size_t)N_NODES * 4);
    int*   ssrc    = (int*)  alloc((size_t)N_EDGES * 4);
    int*   seid    = (int*)  alloc((size_t)N_EDGES * 4);
    (void)ws_size; // requires ~58 MB

    hipMemsetAsync(deg, 0, (size_t)N_NODES * 4, stream);
    hipMemsetAsync(hsum, 0, (size_t)NUM_GRAPHS * HID * 4, stream);
    hipMemsetAsync(cnt, 0, (size_t)NUM_GRAPHS * 4, stream);

    k_degree<<<(N_EDGES + 255) / 256, 256, 0, stream>>>(ei, deg);
    k_scan<<<1, 1024, 0, stream>>>(deg, rowst, cursor);
    k_scatter<<<(N_EDGES + 255) / 256, 256, 0, stream>>>(ei, cursor, ssrc, seid);
    k_init_h<<<N_NODES, 128, 0, stream>>>(x, Win, b_in, h0);

    float* h_cur = h0;
    float* h_nxt = h1;
    const int MG = (N_NODES + 127) / 128;  // 79
    for (int i = 0; i < LAYERS; i++) {
        k_gemm128<<<dim3(MG, HC / 128), 256, 0, stream>>>(
            h_cur, Wl + (size_t)i * HID * HC, bl + (size_t)i * HC, xl, N_NODES, HC);
        k_gemm128<<<dim3(MG, HC / 128), 256, 0, stream>>>(
            h_cur, Wr + (size_t)i * HID * HC, br + (size_t)i * HC, xr, N_NODES, HC);
        if (i > 0) {
            k_gemm128<<<dim3(MG, 1), 256, 0, stream>>>(
                h_cur, Wres + (size_t)(i - 1) * HID * HID, bres + (size_t)(i - 1) * HID,
                resbuf, N_NODES, HID);
        }
        k_edge_fused<<<N_NODES, 128, 0, stream>>>(
            xl, xr, edge_attr, rowst, ssrc, seid,
            We + (size_t)i * EDGE_DIM * HC, att + (size_t)i * HEADS * HID,
            b_gat + (size_t)i * HID, gamma + (size_t)i * HID, beta + (size_t)i * HID,
            resbuf, (i > 0) ? 1 : 0, h_nxt);
        float* tmp = h_cur; h_cur = h_nxt; h_nxt = tmp;
    }

    k_pool<<<N_NODES, 128, 0, stream>>>(h_cur, batch, hsum, cnt);
    k_mlp<<<NUM_GRAPHS, 128, 0, stream>>>(hsum, cnt, W1, b1, W2, b2, W3, b3, out);
}

// Round 2
// 516.166 us; speedup vs baseline: 1.5940x; 1.5940x over previous
//
#include <hip/hip_runtime.h>

#define N_NODES 10000
#define N_EDGES 100000
#define IN_CH 64
#define EDGE_DIM 16
#define HID 128
#define HEADS 4
#define HC 512          // HEADS*HID
#define LAYERS 4
#define NUM_GRAPHS 256
#define NCAT 1152       // HC(xl) + HC(xr) ... wait: 512+512+128 = 1152 packed cols
#define LDP 136         // padded LDS stride (bf16 elems), 272 B = 17*16 -> 16B aligned

typedef __bf16 bf16;
typedef __bf16 bf16x8 __attribute__((ext_vector_type(8)));
typedef __bf16 bf16x4 __attribute__((ext_vector_type(4)));
typedef float floatx4 __attribute__((ext_vector_type(4)));

__device__ __forceinline__ float elu_f(float x) { return x > 0.f ? x : (__expf(x) - 1.f); }

// ---------------- weight prep: WT[l][n][k] bf16 (pre-transposed, packed Wl|Wr|Wres),
// bcat[l][n] fp32. grid = LAYERS*NCAT blocks, 128 threads (k).
__global__ __launch_bounds__(128) void k_prep_w(
    const float* __restrict__ Wl, const float* __restrict__ bl,
    const float* __restrict__ Wr, const float* __restrict__ br,
    const float* __restrict__ Wres, const float* __restrict__ bres,
    bf16* __restrict__ WT, float* __restrict__ bcat) {
    int bid = blockIdx.x;
    int i = bid / NCAT, n = bid % NCAT;
    int k = threadIdx.x;
    float w = 0.f, bias = 0.f;
    if (n < 512) {
        w = Wl[(size_t)i * HID * HC + (size_t)k * HC + n];
        bias = bl[i * HC + n];
    } else if (n < 1024) {
        int nn = n - 512;
        w = Wr[(size_t)i * HID * HC + (size_t)k * HC + nn];
        bias = br[i * HC + nn];
    } else if (i > 0) {
        int nn = n - 1024;
        w = Wres[(size_t)(i - 1) * HID * HID + (size_t)k * HID + nn];
        bias = bres[(i - 1) * HID + nn];
    }
    WT[(size_t)i * NCAT * HID + (size_t)n * HID + k] = (bf16)w;
    if (k == 0) bcat[i * NCAT + n] = bias;
}

// ---------------- h0 = elu(x @ Win + b_in) ----------------
__global__ __launch_bounds__(128) void k_init_h(const float* __restrict__ x,
                                                const float* __restrict__ Win,
                                                const float* __restrict__ b_in,
                                                float* __restrict__ h,
                                                bf16* __restrict__ h_bf) {
    __shared__ float xs[IN_CH];
    int n = blockIdx.x, t = threadIdx.x;
    if (t < IN_CH) xs[t] = x[(size_t)n * IN_CH + t];
    __syncthreads();
    float s = b_in[t];
#pragma unroll 8
    for (int k = 0; k < IN_CH; k++) s = fmaf(xs[k], Win[k * HID + t], s);
    float y = elu_f(s);
    h[(size_t)n * HID + t] = y;
    h_bf[(size_t)n * HID + t] = (bf16)y;
}

// ---------------- MFMA bf16 GEMM: C[M,1152(ld)] = A[M,128] @ WT[nt*128,128]^T + bias
// block 256 (4 waves, 2x2 quadrants of 64x64), tile 128x128, whole K=128 in LDS.
__global__ __launch_bounds__(256, 2) void k_gemm_mfma(
    const bf16* __restrict__ A, const bf16* __restrict__ WT,
    const float* __restrict__ bcat, bf16* __restrict__ C, int M) {
    __shared__ __align__(16) unsigned short As[128 * LDP];
    __shared__ __align__(16) unsigned short Bs[128 * LDP];
    int t = threadIdx.x;
    int r0 = blockIdx.x * 128, c0 = blockIdx.y * 128;
#pragma unroll
    for (int i = 0; i < 8; i++) {
        int idx = t + i * 256;       // 0..2047
        int row = idx >> 4;          // 0..127
        int ch = idx & 15;           // 16B chunk -> elems ch*8
        int r = r0 + row; if (r >= M) r = M - 1;
        uint4 va = *(const uint4*)(A + (size_t)r * HID + ch * 8);
        *(uint4*)&As[row * LDP + ch * 8] = va;
        uint4 vb = *(const uint4*)(WT + (size_t)(c0 + row) * HID + ch * 8);
        *(uint4*)&Bs[row * LDP + ch * 8] = vb;
    }
    __syncthreads();

    int wave = t >> 6, lane = t & 63;
    int wm = wave & 1, wn = wave >> 1;
    int quad = lane >> 4, lm = lane & 15;
    floatx4 zero = {0.f, 0.f, 0.f, 0.f};
    floatx4 acc[4][4];
#pragma unroll
    for (int mi = 0; mi < 4; mi++)
#pragma unroll
        for (int ni = 0; ni < 4; ni++) acc[mi][ni] = zero;

    const unsigned short* Ab = &As[(wm * 64 + lm) * LDP + quad * 8];
    const unsigned short* Bb = &Bs[(wn * 64 + lm) * LDP + quad * 8];
#pragma unroll
    for (int ks = 0; ks < 4; ks++) {
        bf16x8 af[4], bfr[4];
#pragma unroll
        for (int mi = 0; mi < 4; mi++) af[mi] = *(const bf16x8*)(Ab + mi * 16 * LDP + ks * 32);
#pragma unroll
        for (int ni = 0; ni < 4; ni++) bfr[ni] = *(const bf16x8*)(Bb + ni * 16 * LDP + ks * 32);
#pragma unroll
        for (int mi = 0; mi < 4; mi++)
#pragma unroll
            for (int ni = 0; ni < 4; ni++)
                acc[mi][ni] = __builtin_amdgcn_mfma_f32_16x16x32_bf16(af[mi], bfr[ni], acc[mi][ni], 0, 0, 0);
    }

#pragma unroll
    for (int ni = 0; ni < 4; ni++) {
        int col = c0 + wn * 64 + ni * 16 + lm;
        float bias = bcat[col];
#pragma unroll
        for (int mi = 0; mi < 4; mi++) {
#pragma unroll
            for (int r = 0; r < 4; r++) {
                int row = r0 + wm * 64 + mi * 16 + quad * 4 + r;
                if (row < M) C[(size_t)row * NCAT + col] = (bf16)(acc[mi][ni][r] + bias);
            }
        }
    }
}

// ---------------- CSR build ----------------
__global__ void k_degree(const int* __restrict__ ei, int* __restrict__ deg) {
    int e = blockIdx.x * blockDim.x + threadIdx.x;
    if (e < N_EDGES) atomicAdd(&deg[ei[N_EDGES + e]], 1);
}

__global__ __launch_bounds__(1024) void k_scan(const int* __restrict__ deg,
                                               int* __restrict__ row_start,
                                               int* __restrict__ cursor) {
    __shared__ int buf[1024];
    __shared__ int carry_s;
    int t = threadIdx.x;
    if (t == 0) { carry_s = 0; row_start[0] = 0; }
    __syncthreads();
    for (int base = 0; base < N_NODES; base += 1024) {
        int i = base + t;
        int v = (i < N_NODES) ? deg[i] : 0;
        buf[t] = v;
        __syncthreads();
        for (int off = 1; off < 1024; off <<= 1) {
            int add = (t >= off) ? buf[t - off] : 0;
            __syncthreads();
            buf[t] += add;
            __syncthreads();
        }
        int incl = buf[t];
        int carry = carry_s;
        if (i < N_NODES) {
            row_start[i + 1] = carry + incl;
            cursor[i] = carry + incl - v;   // exclusive prefix
        }
        __syncthreads();
        if (t == 1023) carry_s = carry + buf[1023];
        __syncthreads();
    }
}

__global__ void k_scatter(const int* __restrict__ ei, int* __restrict__ cursor,
                          int* __restrict__ ssrc, int* __restrict__ seid) {
    int e = blockIdx.x * blockDim.x + threadIdx.x;
    if (e < N_EDGES) {
        int d = ei[N_EDGES + e];
        int pos = atomicAdd(&cursor[d], 1);
        ssrc[pos] = ei[e];
        seid[pos] = e;
    }
}

// ---------------- fused GATv2 edge phase + head-mean + LN + ELU + residual ----
// one block (128 thr = 2 waves) per destination node. xlr rows packed bf16:
// [0,512)=xl, [512,1024)=xr, [1024,1152)=res. Online softmax, zero atomics.
__global__ __launch_bounds__(128) void k_edge_fused(
    const bf16* __restrict__ xlr,
    const float* __restrict__ edge_attr,
    const int* __restrict__ row_start, const int* __restrict__ ssrc,
    const int* __restrict__ seid,
    const float* __restrict__ We_l, const float* __restrict__ att_l,
    const float* __restrict__ bgat_l, const float* __restrict__ gamma_l,
    const float* __restrict__ beta_l,
    int has_res,
    float* __restrict__ h_out, bf16* __restrict__ hbf_out) {
    int n = blockIdx.x;
    int t = threadIdx.x;
    int wave = t >> 6;
    int lane = t & 63;
    int c0 = wave * 256 + lane * 4;
    int head = c0 >> 7;

    float4 we4[16];
#pragma unroll
    for (int k = 0; k < 16; k++) we4[k] = *(const float4*)(We_l + k * HC + c0);
    float4 att4 = *(const float4*)(att_l + head * HID + (c0 & 127));
    float xr0, xr1, xr2, xr3;
    {
        bf16x4 v = *(const bf16x4*)(xlr + (size_t)n * NCAT + 512 + c0);
        xr0 = (float)v[0]; xr1 = (float)v[1]; xr2 = (float)v[2]; xr3 = (float)v[3];
    }

    float4 acc = {0.f, 0.f, 0.f, 0.f};
    float m_run = -1e30f, l_run = 0.f;

    int e0 = row_start[n], e1 = row_start[n + 1];
    for (int j = e0; j < e1; j++) {
        int s = ssrc[j], eid = seid[j];
        float ea[16];
        {
            const float4* eap = (const float4*)(edge_attr + (size_t)eid * EDGE_DIM);
            float4 a0 = eap[0], a1 = eap[1], a2 = eap[2], a3 = eap[3];
            ea[0]=a0.x; ea[1]=a0.y; ea[2]=a0.z; ea[3]=a0.w;
            ea[4]=a1.x; ea[5]=a1.y; ea[6]=a1.z; ea[7]=a1.w;
            ea[8]=a2.x; ea[9]=a2.y; ea[10]=a2.z; ea[11]=a2.w;
            ea[12]=a3.x; ea[13]=a3.y; ea[14]=a3.z; ea[15]=a3.w;
        }
        float xl0, xl1, xl2, xl3;
        {
            bf16x4 v = *(const bf16x4*)(xlr + (size_t)s * NCAT + c0);
            xl0 = (float)v[0]; xl1 = (float)v[1]; xl2 = (float)v[2]; xl3 = (float)v[3];
        }
        float e4x = 0.f, e4y = 0.f, e4z = 0.f, e4w = 0.f;
#pragma unroll
        for (int k = 0; k < 16; k++) {
            e4x = fmaf(ea[k], we4[k].x, e4x);
            e4y = fmaf(ea[k], we4[k].y, e4y);
            e4z = fmaf(ea[k], we4[k].z, e4z);
            e4w = fmaf(ea[k], we4[k].w, e4w);
        }
        float mx = xl0 + xr0 + e4x; mx = mx > 0.f ? mx : 0.2f * mx;
        float my = xl1 + xr1 + e4y; my = my > 0.f ? my : 0.2f * my;
        float mz = xl2 + xr2 + e4z; mz = mz > 0.f ? mz : 0.2f * mz;
        float mw = xl3 + xr3 + e4w; mw = mw > 0.f ? mw : 0.2f * mw;
        float partial = mx * att4.x + my * att4.y + mz * att4.z + mw * att4.w;
#pragma unroll
        for (int off = 1; off < 32; off <<= 1) partial += __shfl_xor(partial, off, 64);
        float logit = partial;                 // per-head logit, uniform in 32-lane half
        float nm = fmaxf(m_run, logit);
        float sc = __expf(m_run - nm);
        float p  = __expf(logit - nm);
        l_run = l_run * sc + p;
        acc.x = fmaf(p, xl0, acc.x * sc);
        acc.y = fmaf(p, xl1, acc.y * sc);
        acc.z = fmaf(p, xl2, acc.z * sc);
        acc.w = fmaf(p, xl3, acc.w * sc);
        m_run = nm;
    }
    float inv = 1.f / (l_run + 1e-16f);

    __shared__ float sout[HC];
    __shared__ float red[4];
    sout[c0 + 0] = acc.x * inv;
    sout[c0 + 1] = acc.y * inv;
    sout[c0 + 2] = acc.z * inv;
    sout[c0 + 3] = acc.w * inv;
    __syncthreads();

    int c = t;
    float v = 0.25f * (sout[c] + sout[c + 128] + sout[c + 256] + sout[c + 384]) + bgat_l[c];
    float s1 = v, s2 = v * v;
#pragma unroll
    for (int off = 1; off < 64; off <<= 1) {
        s1 += __shfl_xor(s1, off, 64);
        s2 += __shfl_xor(s2, off, 64);
    }
    if (lane == 0) { red[wave * 2] = s1; red[wave * 2 + 1] = s2; }
    __syncthreads();
    s1 = red[0] + red[2];
    s2 = red[1] + red[3];
    float mu = s1 * (1.f / HID);
    float var = s2 * (1.f / HID) - mu * mu;
    float rstd = rsqrtf(var + 1e-5f);
    float y = fmaf(gamma_l[c] * (v - mu), rstd, beta_l[c]);
    y = elu_f(y);
    if (has_res) y += (float)xlr[(size_t)n * NCAT + 1024 + c];
    h_out[(size_t)n * HID + c] = y;
    hbf_out[(size_t)n * HID + c] = (bf16)y;
}

// ---------------- pooling + MLP ----------------
__global__ __launch_bounds__(128) void k_pool(const float* __restrict__ h,
                                              const int* __restrict__ batch,
                                              float* __restrict__ hsum,
                                              int* __restrict__ cnt) {
    int n = blockIdx.x, c = threadIdx.x;
    int g = batch[n];
    atomicAdd(&hsum[(size_t)g * HID + c], h[(size_t)n * HID + c]);
    if (c == 0) atomicAdd(&cnt[g], 1);
}

__global__ __launch_bounds__(128) void k_mlp(const float* __restrict__ hsum,
                                             const int* __restrict__ cnt,
                                             const float* __restrict__ W1, const float* __restrict__ b1,
                                             const float* __restrict__ W2, const float* __restrict__ b2,
                                             const float* __restrict__ W3, const float* __restrict__ b3,
                                             float* __restrict__ out) {
    int g = blockIdx.x, t = threadIdx.x;
    __shared__ float hg[HID], z1[HID], z2[64];
    float invc = 1.f / fmaxf((float)cnt[g], 1.f);
    hg[t] = hsum[(size_t)g * HID + t] * invc;
    __syncthreads();
    float s = b1[t];
#pragma unroll 8
    for (int k = 0; k < HID; k++) s = fmaf(hg[k], W1[k * HID + t], s);
    z1[t] = fmaxf(s, 0.f);
    __syncthreads();
    if (t < 64) {
        float s2 = b2[t];
#pragma unroll 8
        for (int k = 0; k < HID; k++) s2 = fmaf(z1[k], W2[k * 64 + t], s2);
        z2[t] = fmaxf(s2, 0.f);
    }
    __syncthreads();
    if (t < 64) {
        float s3 = z2[t] * W3[t];
#pragma unroll
        for (int off = 1; off < 64; off <<= 1) s3 += __shfl_xor(s3, off, 64);
        if (t == 0) out[g] = s3 + b3[0];
    }
}

// ---------------- host launcher ----------------
extern "C" void kernel_launch(void* const* d_in, const int* in_sizes, int n_in,
                              void* d_out, int out_size, void* d_ws, size_t ws_size,
                              hipStream_t stream) {
    const float* x         = (const float*)d_in[0];
    const int*   ei        = (const int*)  d_in[1];
    const float* edge_attr = (const float*)d_in[2];
    const int*   batch     = (const int*)  d_in[3];
    const float* Win       = (const float*)d_in[4];
    const float* b_in      = (const float*)d_in[5];
    const float* Wl        = (const float*)d_in[6];
    const float* bl        = (const float*)d_in[7];
    const float* Wr        = (const float*)d_in[8];
    const float* br        = (const float*)d_in[9];
    const float* We        = (const float*)d_in[10];
    const float* att       = (const float*)d_in[11];
    const float* b_gat     = (const float*)d_in[12];
    const float* gamma     = (const float*)d_in[13];
    const float* beta      = (const float*)d_in[14];
    const float* Wres      = (const float*)d_in[15];
    const float* bres      = (const float*)d_in[16];
    const float* W1        = (const float*)d_in[17];
    const float* b1        = (const float*)d_in[18];
    const float* W2        = (const float*)d_in[19];
    const float* b2        = (const float*)d_in[20];
    const float* W3        = (const float*)d_in[21];
    const float* b3        = (const float*)d_in[22];
    float* out = (float*)d_out;

    char* ws = (char*)d_ws;
    size_t off = 0;
    auto alloc = [&](size_t bytes) -> void* {
        void* p = ws + off;
        off = (off + bytes + 255) & ~(size_t)255;
        return p;
    };
    float* h0      = (float*)alloc((size_t)N_NODES * HID * 4);
    float* h1      = (float*)alloc((size_t)N_NODES * HID * 4);
    bf16*  h_bf    = (bf16*) alloc((size_t)N_NODES * HID * 2);
    bf16*  xlr     = (bf16*) alloc((size_t)N_NODES * NCAT * 2);
    bf16*  WT      = (bf16*) alloc((size_t)LAYERS * NCAT * HID * 2);
    float* bcat    = (float*)alloc((size_t)LAYERS * NCAT * 4);
    float* hsum    = (float*)alloc((size_t)NUM_GRAPHS * HID * 4);
    int*   cnt     = (int*)  alloc((size_t)NUM_GRAPHS * 4);
    int*   deg     = (int*)  alloc((size_t)N_NODES * 4);
    int*   rowst   = (int*)  alloc((size_t)(N_NODES + 1) * 4);
    int*   cursor  = (int*)  alloc((size_t)N_NODES * 4);
    int*   ssrc    = (int*)  alloc((size_t)N_EDGES * 4);
    int*   seid    = (int*)  alloc((size_t)N_EDGES * 4);
    (void)ws_size; // requires ~38 MB

    hipMemsetAsync(deg, 0, (size_t)N_NODES * 4, stream);
    hipMemsetAsync(hsum, 0, (size_t)NUM_GRAPHS * HID * 4, stream);
    hipMemsetAsync(cnt, 0, (size_t)NUM_GRAPHS * 4, stream);

    k_prep_w<<<LAYERS * NCAT, 128, 0, stream>>>(Wl, bl, Wr, br, Wres, bres, WT, bcat);
    k_degree<<<(N_EDGES + 255) / 256, 256, 0, stream>>>(ei, deg);
    k_scan<<<1, 1024, 0, stream>>>(deg, rowst, cursor);
    k_scatter<<<(N_EDGES + 255) / 256, 256, 0, stream>>>(ei, cursor, ssrc, seid);
    k_init_h<<<N_NODES, 128, 0, stream>>>(x, Win, b_in, h0, h_bf);

    float* h_cur = h0;
    float* h_nxt = h1;
    const int MG = (N_NODES + 127) / 128;  // 79
    for (int i = 0; i < LAYERS; i++) {
        int ntiles = (i > 0) ? (NCAT / 128) : (1024 / 128);
        k_gemm_mfma<<<dim3(MG, ntiles), 256, 0, stream>>>(
            h_bf, WT + (size_t)i * NCAT * HID, bcat + (size_t)i * NCAT, xlr, N_NODES);
        k_edge_fused<<<N_NODES, 128, 0, stream>>>(
            xlr, edge_attr, rowst, ssrc, seid,
            We + (size_t)i * EDGE_DIM * HC, att + (size_t)i * HEADS * HID,
            b_gat + (size_t)i * HID, gamma + (size_t)i * HID, beta + (size_t)i * HID,
            (i > 0) ? 1 : 0, h_nxt, h_bf);
        float* tmp = h_cur; h_cur = h_nxt; h_nxt = tmp;
    }

    k_pool<<<N_NODES, 128, 0, stream>>>(h_cur, batch, hsum, cnt);
    k_mlp<<<NUM_GRAPHS, 128, 0, stream>>>(hsum, cnt, W1, b1, W2, b2, W3, b3, out);
}